// Round 6
// baseline (433.632 us; speedup 1.0000x reference)
//
#include <hip/hip_runtime.h>
#include <math.h>

#define NN 50000
#define EPSM 1e-7f
#define BN_EPS 1e-5f
#define NBK 391                 // ceil(50000/128) buckets of 128 nodes
#define LOG2E 1.44269504088896340736f
#define MM_REP 8                // mm replicas (colmin/max) to avoid atomic storms
#define MOM_BLOCKS 196          // moments partial blocks (256 rows each)
#define MOM_STRIDE 4352         // 4096 M + 256 colsum slots per partial

// native 2^x : v_exp_f32 (arg <= 0 here; FTZ for very negative arg is fine).
#if defined(__has_builtin)
#if __has_builtin(__builtin_amdgcn_exp2f)
#define HAVE_EXP2_BUILTIN 1
#endif
#endif
__device__ __forceinline__ float fast_exp2(float v){
#ifdef HAVE_EXP2_BUILTIN
  return __builtin_amdgcn_exp2f(v);
#else
  return exp2f(v);
#endif
}

// ---------------- bucket-sorted CSR build (line-coalesced writes) ----------------

__global__ __launch_bounds__(256) void bucket_hist_kernel(
    const int* __restrict__ dst, int* __restrict__ bhist, int E,
    unsigned* __restrict__ mm0){
  __shared__ int h[NBK];
  int t = threadIdx.x;
  if (blockIdx.x == 0){
    // seed mm0 AND mm1 (contiguous): min seed FLT_MAX / max seed 0
    for (int i = t; i < 2 * MM_REP * 128; i += 256)
      mm0[i] = ((i & 127) < 64) ? 0x7F7FFFFFu : 0u;
  }
  for (int i = t; i < NBK; i += 256) h[i] = 0;
  __syncthreads();
  int e0 = blockIdx.x * 4096;
  int cnt = min(4096, E - e0);
  for (int i = t; i < cnt; i += 256) atomicAdd(&h[dst[e0 + i] >> 7], 1);
  __syncthreads();
  for (int i = t; i < NBK; i += 256) if (h[i]) atomicAdd(&bhist[i], h[i]);
}

__global__ void bucket_scan_kernel(const int* __restrict__ bhist,
                                   int* __restrict__ bbase, int* __restrict__ gcur){
  int lane = threadIdx.x;   // 64 threads
  int loc[7]; int s = 0;
#pragma unroll
  for (int k = 0; k < 7; ++k){
    int i = lane * 7 + k;
    int v = (i < NBK) ? bhist[i] : 0;
    loc[k] = s; s += v;
  }
  int sc = s;
#pragma unroll
  for (int o = 1; o < 64; o <<= 1){
    int n = __shfl_up(sc, o);
    if (lane >= o) sc += n;
  }
  int exc = sc - s;
#pragma unroll
  for (int k = 0; k < 7; ++k){
    int i = lane * 7 + k;
    if (i < NBK){ bbase[i] = exc + loc[k]; gcur[i] = exc + loc[k]; }
    else if (i == NBK) bbase[i] = exc + loc[k];   // total == E
  }
}

__global__ __launch_bounds__(256) void bucket_scatter_kernel(
    const int* __restrict__ src, const int* __restrict__ dst,
    int* __restrict__ gcur, unsigned* __restrict__ packed_g, int E){
  __shared__ int hist[NBK], offs[NBK], gb[NBK], curk[NBK];
  __shared__ unsigned stage[4096];
  __shared__ int gpos[4096];
  int t = threadIdx.x;
  for (int i = t; i < NBK; i += 256) hist[i] = 0;
  __syncthreads();
  int e0 = blockIdx.x * 4096;
  int cnt = min(4096, E - e0);
  unsigned pk[16]; int bk[16];
  int nmine = 0;
  for (int i = t; i < cnt; i += 256){
    int d = dst[e0 + i], s = src[e0 + i];
    pk[nmine] = ((unsigned)d << 16) | (unsigned)s;
    bk[nmine] = d >> 7;
    atomicAdd(&hist[bk[nmine]], 1);
    ++nmine;
  }
  __syncthreads();
  if (t < 64){                      // wave-0 scan of 391 counts (7 per lane)
    int loc[7]; int s = 0;
#pragma unroll
    for (int k = 0; k < 7; ++k){
      int i = t * 7 + k;
      int v = (i < NBK) ? hist[i] : 0;
      loc[k] = s; s += v;
    }
    int sc = s;
#pragma unroll
    for (int o = 1; o < 64; o <<= 1){
      int n = __shfl_up(sc, o);
      if (t >= o) sc += n;
    }
    int exc = sc - s;
#pragma unroll
    for (int k = 0; k < 7; ++k){
      int i = t * 7 + k;
      if (i < NBK) offs[i] = exc + loc[k];
    }
  }
  __syncthreads();
  for (int i = t; i < NBK; i += 256){
    int h = hist[i];
    gb[i] = h ? atomicAdd(&gcur[i], h) : 0;
    curk[i] = offs[i];
  }
  __syncthreads();
  for (int k = 0; k < nmine; ++k){
    int b = bk[k];
    int p = atomicAdd(&curk[b], 1);
    stage[p] = pk[k];
    gpos[p] = gb[b] + (p - offs[b]);
  }
  __syncthreads();
  for (int j = t; j < cnt; j += 256) packed_g[gpos[j]] = stage[j];   // run-coalesced
}

__global__ __launch_bounds__(256) void bucket_place_kernel(
    const unsigned* __restrict__ packed_g, const int* __restrict__ bbase,
    int* __restrict__ start_g, int* __restrict__ end_g,
    unsigned short* __restrict__ srcs_g, int N){
  __shared__ int deg[128], off[128], cur[128];
  __shared__ int sstage[4096];
  int b = blockIdx.x, t = threadIdx.x;
  int beg = bbase[b], cnt = bbase[b + 1] - beg;
  if (t < 128) deg[t] = 0;
  __syncthreads();
  for (int j = t; j < cnt; j += 256)
    atomicAdd(&deg[(packed_g[beg + j] >> 16) & 127], 1);
  __syncthreads();
  if (t < 64){                      // wave-0 scan of 128 (2 per lane)
    int i0 = t * 2;
    int v0 = deg[i0], v1 = deg[i0 + 1];
    int s = v0 + v1;
    int sc = s;
#pragma unroll
    for (int o = 1; o < 64; o <<= 1){
      int n = __shfl_up(sc, o);
      if (t >= o) sc += n;
    }
    int exc = sc - s;
    off[i0] = exc; off[i0 + 1] = exc + v0;
  }
  __syncthreads();
  int node0 = b * 128;
  if (t < 128){
    int node = node0 + t;
    if (node < N){
      start_g[node] = beg + off[t];
      end_g[node] = beg + off[t] + deg[t];
    }
    cur[t] = off[t];
  }
  __syncthreads();
  if (cnt <= 4096){
    for (int j = t; j < cnt; j += 256){
      unsigned p = packed_g[beg + j];
      int lp = atomicAdd(&cur[(p >> 16) & 127], 1);
      sstage[lp] = (int)(p & 0xFFFFu);
    }
    __syncthreads();
    for (int j = t; j < cnt; j += 256)
      srcs_g[beg + j] = (unsigned short)sstage[j];   // coalesced
  } else {                          // freak-bucket fallback (never for random graph)
    for (int j = t; j < cnt; j += 256){
      unsigned p = packed_g[beg + j];
      int lp = atomicAdd(&cur[(p >> 16) & 127], 1);
      srcs_g[beg + lp] = (unsigned short)(p & 0xFFFFu);
    }
  }
}

// ---------------- layer-0 only: bf16 message table [node][64] + column min/max ----

__global__ __launch_bounds__(256) void colminmax_kernel(
    const float* __restrict__ x, unsigned* __restrict__ mm,
    unsigned short* __restrict__ mh, int N){
  __shared__ unsigned smn[256], smx[256];
  int c = threadIdx.x & 63;
  int slot = blockIdx.x * 4 + (threadIdx.x >> 6);
  float mx = 0.f, mn = 1e30f;
  for (int r = slot; r < N; r += 256 * 4){
    float m = fmaxf(x[r * 64 + c], 0.f) + EPSM;
    unsigned u = __float_as_uint(m);
    u += 0x7FFFu + ((u >> 16) & 1u);         // RNE to bf16
    unsigned short us = (unsigned short)(u >> 16);
    mh[r * 64 + c] = us;
    float mb = __uint_as_float(((unsigned)us) << 16);
    mx = fmaxf(mx, mb);
    mn = fminf(mn, mb);
  }
  smn[threadIdx.x] = __float_as_uint(mn);
  smx[threadIdx.x] = __float_as_uint(mx);
  __syncthreads();
  if (threadIdx.x < 64){
    int rep = (blockIdx.x & (MM_REP - 1)) * 128;
    unsigned a = smn[c], b = smn[c + 64], d = smn[c + 128], e = smn[c + 192];
    atomicMin(&mm[rep + c], min(min(a, b), min(d, e)));
    a = smx[c]; b = smx[c + 64]; d = smx[c + 128]; e = smx[c + 192];
    atomicMax(&mm[rep + 64 + c], max(max(a, b), max(d, e)));
  }
}

// ------------- single-pass softmax aggregation -------------
// wave = 4 edge slots x 16 lanes; lane loads a uint2 = 4 bf16 channels. Native
// v_exp_f32 in exp2 domain; per-channel bound B from LDS (block-level reduce).

__global__ __launch_bounds__(256) void aggregate_kernel(
    const float* __restrict__ x, const uint2* __restrict__ mh2,
    const int* __restrict__ start, const int* __restrict__ segend,
    const unsigned short* __restrict__ srcs, const float* __restrict__ tptr,
    int layer, const unsigned* __restrict__ mm, float* __restrict__ h0, int N){
  __shared__ float4 Bs4[16];                // B[64] per-channel log2-domain bound
  int t = threadIdx.x;
  float t2 = tptr[layer] * LOG2E;
  if (t < 64){
    unsigned mn = 0x7F7FFFFFu, mx = 0u;     // positive floats: uint cmp == float cmp
#pragma unroll
    for (int r = 0; r < MM_REP; ++r){
      mn = min(mn, mm[r * 128 + t]);
      mx = max(mx, mm[r * 128 + 64 + t]);
    }
    ((float*)Bs4)[t] = fmaxf(t2 * __uint_as_float(mx), t2 * __uint_as_float(mn));
  }
  __syncthreads();
  int node = blockIdx.x * 4 + (t >> 6);
  if (node >= N) return;
  int lane = t & 63;
  int slot = lane >> 4, cp = lane & 15;     // channels 4cp .. 4cp+3
  float4 B = Bs4[cp];
  int beg = start[node], end = segend[node];
  float d0 = 0.f, d1 = 0.f, d2 = 0.f, d3 = 0.f;
  float n0 = 0.f, n1 = 0.f, n2 = 0.f, n3 = 0.f;
  int e = beg;
  for (; e + 7 < end; e += 8){              // 8 edges per wave-iteration
    int sA = srcs[e + slot];
    int sB = srcs[e + 4 + slot];
    uint2 uA = mh2[sA * 16 + cp];
    uint2 uB = mh2[sB * 16 + cp];
    float a0 = __uint_as_float(uA.x << 16), a1 = __uint_as_float(uA.x & 0xFFFF0000u);
    float a2 = __uint_as_float(uA.y << 16), a3 = __uint_as_float(uA.y & 0xFFFF0000u);
    float b0 = __uint_as_float(uB.x << 16), b1 = __uint_as_float(uB.x & 0xFFFF0000u);
    float b2 = __uint_as_float(uB.y << 16), b3 = __uint_as_float(uB.y & 0xFFFF0000u);
    float pA0 = fast_exp2(fmaf(a0, t2, -B.x)), pA1 = fast_exp2(fmaf(a1, t2, -B.y));
    float pA2 = fast_exp2(fmaf(a2, t2, -B.z)), pA3 = fast_exp2(fmaf(a3, t2, -B.w));
    float pB0 = fast_exp2(fmaf(b0, t2, -B.x)), pB1 = fast_exp2(fmaf(b1, t2, -B.y));
    float pB2 = fast_exp2(fmaf(b2, t2, -B.z)), pB3 = fast_exp2(fmaf(b3, t2, -B.w));
    d0 += pA0 + pB0; n0 += a0 * pA0 + b0 * pB0;
    d1 += pA1 + pB1; n1 += a1 * pA1 + b1 * pB1;
    d2 += pA2 + pB2; n2 += a2 * pA2 + b2 * pB2;
    d3 += pA3 + pB3; n3 += a3 * pA3 + b3 * pB3;
  }
  for (; e + slot < end; e += 4){           // tail: up to 7 edges
    int s = srcs[e + slot];
    uint2 u = mh2[s * 16 + cp];
    float a0 = __uint_as_float(u.x << 16), a1 = __uint_as_float(u.x & 0xFFFF0000u);
    float a2 = __uint_as_float(u.y << 16), a3 = __uint_as_float(u.y & 0xFFFF0000u);
    float p0 = fast_exp2(fmaf(a0, t2, -B.x)), p1 = fast_exp2(fmaf(a1, t2, -B.y));
    float p2 = fast_exp2(fmaf(a2, t2, -B.z)), p3 = fast_exp2(fmaf(a3, t2, -B.w));
    d0 += p0; n0 += a0 * p0;  d1 += p1; n1 += a1 * p1;
    d2 += p2; n2 += a2 * p2;  d3 += p3; n3 += a3 * p3;
  }
  d0 += __shfl_xor(d0, 16); d1 += __shfl_xor(d1, 16);
  d2 += __shfl_xor(d2, 16); d3 += __shfl_xor(d3, 16);
  n0 += __shfl_xor(n0, 16); n1 += __shfl_xor(n1, 16);
  n2 += __shfl_xor(n2, 16); n3 += __shfl_xor(n3, 16);
  d0 += __shfl_xor(d0, 32); d1 += __shfl_xor(d1, 32);
  d2 += __shfl_xor(d2, 32); d3 += __shfl_xor(d3, 32);
  n0 += __shfl_xor(n0, 32); n1 += __shfl_xor(n1, 32);
  n2 += __shfl_xor(n2, 32); n3 += __shfl_xor(n3, 32);
  if (slot == 0){
    float4 xv = ((const float4*)x)[node * 16 + cp];
    float4 o;
    o.x = n0 / (d0 + 1e-16f) + xv.x;
    o.y = n1 / (d1 + 1e-16f) + xv.y;
    o.z = n2 / (d2 + 1e-16f) + xv.z;
    o.w = n3 / (d3 + 1e-16f) + xv.w;
    ((float4*)h0)[node * 16 + cp] = o;
  }
}

// ---------------- moments: per-block partial M = h0^T h0 and colsum s --------
// 196 blocks x 256 rows. Each thread owns a 4x4 tile of M in registers.
// part[b] layout: [4096 M][256 colsum slots (4 row-groups x 64 ch)].

__global__ __launch_bounds__(256) void moments_kernel(
    const float* __restrict__ h0, float* __restrict__ part){
  __shared__ float rs[16][64];
  int t = threadIdx.x;
  float m[4][4];
#pragma unroll
  for (int a = 0; a < 4; ++a)
#pragma unroll
    for (int b = 0; b < 4; ++b) m[a][b] = 0.f;
  float cs = 0.f;
  int i0 = (t >> 4) * 4, j0 = (t & 15) * 4;
  int lr = t >> 4, lq = t & 15;             // staging: row lr, float4 lq
  int ch = t & 63, r0 = t >> 6;             // colsum: channel ch, rows r0,r0+4,..
  int base = blockIdx.x * 256;
  for (int c = 0; c < 16; ++c){
    __syncthreads();
    int gr = base + c * 16 + lr;
    float4 v = make_float4(0.f, 0.f, 0.f, 0.f);
    if (gr < NN) v = ((const float4*)h0)[gr * 16 + lq];
    *(float4*)&rs[lr][lq * 4] = v;
    __syncthreads();
#pragma unroll
    for (int rr = 0; rr < 16; ++rr){
      float4 av = *(const float4*)&rs[rr][i0];
      float4 bv = *(const float4*)&rs[rr][j0];
      m[0][0] += av.x * bv.x; m[0][1] += av.x * bv.y;
      m[0][2] += av.x * bv.z; m[0][3] += av.x * bv.w;
      m[1][0] += av.y * bv.x; m[1][1] += av.y * bv.y;
      m[1][2] += av.y * bv.z; m[1][3] += av.y * bv.w;
      m[2][0] += av.z * bv.x; m[2][1] += av.z * bv.y;
      m[2][2] += av.z * bv.z; m[2][3] += av.z * bv.w;
      m[3][0] += av.w * bv.x; m[3][1] += av.w * bv.y;
      m[3][2] += av.w * bv.z; m[3][3] += av.w * bv.w;
    }
    cs += rs[r0][ch] + rs[r0 + 4][ch] + rs[r0 + 8][ch] + rs[r0 + 12][ch];
  }
  float* pb = part + blockIdx.x * MOM_STRIDE;
#pragma unroll
  for (int a = 0; a < 4; ++a)
    *(float4*)&pb[(i0 + a) * 64 + j0] = make_float4(m[a][0], m[a][1], m[a][2], m[a][3]);
  pb[4096 + t] = cs;
}

// ---------------- stats: reduce partials, compute BN scale/shift -------------
// 1 block. var_j = (w_j^T M w_j + 2 b_j s^T w_j)/N + b_j^2 - mean_j^2 (exact).

__global__ __launch_bounds__(256) void stats_kernel(
    const float* __restrict__ part, const float* __restrict__ W1,
    const float* __restrict__ b1, const float* __restrict__ gamma,
    const float* __restrict__ beta, int layer, float* __restrict__ ssg){
  __shared__ float M[64][64];
  __shared__ float s[64];
  __shared__ float w[64][128];
  __shared__ float qp[2][128], swp[2][128];
  int t = threadIdx.x;
  int i0 = (t >> 4) * 4, j0 = (t & 15) * 4;
  float a0x=0,a0y=0,a0z=0,a0w=0, a1x=0,a1y=0,a1z=0,a1w=0;
  float a2x=0,a2y=0,a2z=0,a2w=0, a3x=0,a3y=0,a3z=0,a3w=0;
  for (int p = 0; p < MOM_BLOCKS; ++p){
    const float* pb = part + p * MOM_STRIDE;
    float4 v0 = *(const float4*)&pb[(i0 + 0) * 64 + j0];
    float4 v1 = *(const float4*)&pb[(i0 + 1) * 64 + j0];
    float4 v2 = *(const float4*)&pb[(i0 + 2) * 64 + j0];
    float4 v3 = *(const float4*)&pb[(i0 + 3) * 64 + j0];
    a0x += v0.x; a0y += v0.y; a0z += v0.z; a0w += v0.w;
    a1x += v1.x; a1y += v1.y; a1z += v1.z; a1w += v1.w;
    a2x += v2.x; a2y += v2.y; a2z += v2.z; a2w += v2.w;
    a3x += v3.x; a3y += v3.y; a3z += v3.z; a3w += v3.w;
  }
  *(float4*)&M[i0 + 0][j0] = make_float4(a0x, a0y, a0z, a0w);
  *(float4*)&M[i0 + 1][j0] = make_float4(a1x, a1y, a1z, a1w);
  *(float4*)&M[i0 + 2][j0] = make_float4(a2x, a2y, a2z, a2w);
  *(float4*)&M[i0 + 3][j0] = make_float4(a3x, a3y, a3z, a3w);
  if (t < 64){
    float v = 0.f;
    for (int p = 0; p < MOM_BLOCKS; ++p){
      const float* pc = part + p * MOM_STRIDE + 4096;
      v += (pc[t] + pc[64 + t]) + (pc[128 + t] + pc[192 + t]);
    }
    s[t] = v;
  }
  const float4* wg = (const float4*)W1;
  for (int i = t; i < 2048; i += 256) ((float4*)w)[i] = wg[i];
  __syncthreads();
  int j = t & 127, half = t >> 7;
  float q = 0.f, sw = 0.f;
  for (int i = half * 32; i < half * 32 + 32; ++i){
    float dot = 0.f;
#pragma unroll 8
    for (int k = 0; k < 64; ++k) dot += M[i][k] * w[k][j];
    q += w[i][j] * dot;
  }
  for (int k = half * 32; k < half * 32 + 32; ++k) sw += s[k] * w[k][j];
  qp[half][j] = q; swp[half][j] = sw;
  __syncthreads();
  if (t < 128){
    float qt = qp[0][t] + qp[1][t];
    float swt = swp[0][t] + swp[1][t];
    float bj = b1[t];
    float invN = 1.f / (float)NN;
    float mean = swt * invN + bj;
    float e2 = (qt + 2.f * bj * swt) * invN + bj * bj;
    float var = fmaxf(e2 - mean * mean, 0.f);
    float sc = gamma[layer * 128 + t] / sqrtf(var + BN_EPS);
    ssg[t] = sc;
    ssg[128 + t] = beta[layer * 128 + t] - mean * sc;
  }
}

// ---------------- fused MLP: out = relu( relu(BN(h0@W1+b1)) @ W2 + b2 ) -------
// BN scale/shift precomputed (ssg). h1 never touches HBM: gemm1 accumulators
// are BN+relu'd in registers, staged to LDS, consumed by gemm2 in-place.
// Layer 0 also emits next layer's bf16 message table + column min/max.

__global__ __launch_bounds__(256) void fused_mlp_kernel(
    const float* __restrict__ h0, const float* __restrict__ W1,
    const float* __restrict__ b1, const float* __restrict__ ssg,
    const float* __restrict__ W2, const float* __restrict__ b2,
    float* __restrict__ xout, int N,
    unsigned* __restrict__ mm_next, unsigned short* __restrict__ mh_next){
  __shared__ float lds[64 * 132];   // phase A: [64][68] h0 tile; phase B: [64][132] h1'
  __shared__ float ss[256];
  __shared__ unsigned smn[64], smx[64];
  int t = threadIdx.x;
  ss[t] = ssg[t];
  if (t < 64){ smn[t] = 0x7F7FFFFFu; smx[t] = 0u; }
  int row0 = blockIdx.x * 64;
#pragma unroll
  for (int i = 0; i < 4; ++i){
    int li = t + 256 * i;
    int r = li >> 4, q = li & 15;
    int gr = row0 + r;
    float4 v = make_float4(0.f, 0.f, 0.f, 0.f);
    if (gr < N) v = ((const float4*)h0)[gr * 16 + q];
    *(float4*)&lds[r * 68 + q * 4] = v;
  }
  __syncthreads();
  // ---- gemm1: acc1[8][4], rows tr*8.., cols tc*4.. ----
  int tc = t & 31, tr = t >> 5;
  float4 bias1 = ((const float4*)b1)[tc];
  float acc1[8][4];
#pragma unroll
  for (int r = 0; r < 8; ++r){
    acc1[r][0] = bias1.x; acc1[r][1] = bias1.y;
    acc1[r][2] = bias1.z; acc1[r][3] = bias1.w;
  }
  const float4* wg1 = (const float4*)W1;    // [64][32] float4, L1/L2-resident
#pragma unroll 2
  for (int k = 0; k < 64; k += 4){
    float4 w0 = wg1[(k + 0) * 32 + tc];
    float4 w1 = wg1[(k + 1) * 32 + tc];
    float4 w2 = wg1[(k + 2) * 32 + tc];
    float4 w3 = wg1[(k + 3) * 32 + tc];
#pragma unroll
    for (int r = 0; r < 8; ++r){
      float4 a = *(const float4*)&lds[(tr * 8 + r) * 68 + k];
      acc1[r][0] += a.x * w0.x + a.y * w1.x + a.z * w2.x + a.w * w3.x;
      acc1[r][1] += a.x * w0.y + a.y * w1.y + a.z * w2.y + a.w * w3.y;
      acc1[r][2] += a.x * w0.z + a.y * w1.z + a.z * w2.z + a.w * w3.z;
      acc1[r][3] += a.x * w0.w + a.y * w1.w + a.z * w2.w + a.w * w3.w;
    }
  }
  __syncthreads();   // all phase-A reads complete before overwriting LDS
  // ---- BN + relu in registers -> phase-B LDS [64][132] ----
  float4 sc4 = *(const float4*)&ss[tc * 4];
  float4 sh4 = *(const float4*)&ss[128 + tc * 4];
#pragma unroll
  for (int r = 0; r < 8; ++r){
    float4 o;
    o.x = fmaxf(acc1[r][0] * sc4.x + sh4.x, 0.f);
    o.y = fmaxf(acc1[r][1] * sc4.y + sh4.y, 0.f);
    o.z = fmaxf(acc1[r][2] * sc4.z + sh4.z, 0.f);
    o.w = fmaxf(acc1[r][3] * sc4.w + sh4.w, 0.f);
    *(float4*)&lds[(tr * 8 + r) * 132 + tc * 4] = o;
  }
  __syncthreads();
  // ---- gemm2: acc2[4][4], rows tr2*4.., cols tc2*4.. of 64 ----
  int tc2 = t & 15, tr2 = t >> 4;
  float4 bias2 = ((const float4*)b2)[tc2];
  float acc2[4][4];
#pragma unroll
  for (int r = 0; r < 4; ++r){
    acc2[r][0] = bias2.x; acc2[r][1] = bias2.y;
    acc2[r][2] = bias2.z; acc2[r][3] = bias2.w;
  }
  const float4* wg2 = (const float4*)W2;    // [128][16] float4
#pragma unroll 2
  for (int k = 0; k < 128; k += 4){
    float4 w0 = wg2[(k + 0) * 16 + tc2];
    float4 w1 = wg2[(k + 1) * 16 + tc2];
    float4 w2 = wg2[(k + 2) * 16 + tc2];
    float4 w3 = wg2[(k + 3) * 16 + tc2];
#pragma unroll
    for (int r = 0; r < 4; ++r){
      float4 a = *(const float4*)&lds[(tr2 * 4 + r) * 132 + k];
      acc2[r][0] += a.x * w0.x + a.y * w1.x + a.z * w2.x + a.w * w3.x;
      acc2[r][1] += a.x * w0.y + a.y * w1.y + a.z * w2.y + a.w * w3.y;
      acc2[r][2] += a.x * w0.z + a.y * w1.z + a.z * w2.z + a.w * w3.z;
      acc2[r][3] += a.x * w0.w + a.y * w1.w + a.z * w2.w + a.w * w3.w;
    }
  }
  unsigned mnv[4] = {0x7F7FFFFFu, 0x7F7FFFFFu, 0x7F7FFFFFu, 0x7F7FFFFFu};
  unsigned mxv[4] = {0u, 0u, 0u, 0u};
#pragma unroll
  for (int r = 0; r < 4; ++r){
    int gr = row0 + tr2 * 4 + r;
    if (gr < N){
      float o0 = fmaxf(acc2[r][0], 0.f), o1 = fmaxf(acc2[r][1], 0.f);
      float o2 = fmaxf(acc2[r][2], 0.f), o3 = fmaxf(acc2[r][3], 0.f);
      *(float4*)&xout[gr * 64 + tc2 * 4] = make_float4(o0, o1, o2, o3);
      if (mh_next != 0){
        unsigned us[4];
        float ov[4] = {o0, o1, o2, o3};
#pragma unroll
        for (int j = 0; j < 4; ++j){
          unsigned u = __float_as_uint(ov[j] + EPSM);
          u += 0x7FFFu + ((u >> 16) & 1u);       // RNE to bf16
          us[j] = u >> 16;
          unsigned fb = us[j] << 16;
          mnv[j] = min(mnv[j], fb);
          mxv[j] = max(mxv[j], fb);
        }
        ((uint2*)mh_next)[gr * 16 + tc2] =
            make_uint2(us[0] | (us[1] << 16), us[2] | (us[3] << 16));
      }
    }
  }
  if (mh_next != 0){
    __syncthreads();
#pragma unroll
    for (int j = 0; j < 4; ++j){
      atomicMin(&smn[tc2 * 4 + j], mnv[j]);
      atomicMax(&smx[tc2 * 4 + j], mxv[j]);
    }
    __syncthreads();
    if (t < 64){
      int rep = (blockIdx.x & (MM_REP - 1)) * 128;
      atomicMin(&mm_next[rep + t], smn[t]);
      atomicMax(&mm_next[rep + 64 + t], smx[t]);
    }
  }
}

extern "C" void kernel_launch(void* const* d_in, const int* in_sizes, int n_in,
                              void* d_out, int out_size, void* d_ws, size_t ws_size,
                              hipStream_t stream) {
  const float* x0    = (const float*)d_in[0];
  const int*   ei    = (const int*)d_in[1];
  const float* W1    = (const float*)d_in[2];
  const float* b1    = (const float*)d_in[3];
  const float* gamma = (const float*)d_in[4];
  const float* beta  = (const float*)d_in[5];
  const float* W2    = (const float*)d_in[6];
  const float* b2    = (const float*)d_in[7];
  const float* tptr  = (const float*)d_in[8];

  const int N = NN;
  const int E = in_sizes[1] / 2;
  const int* src = ei;
  const int* dst = ei + E;

  float* ws  = (float*)d_ws;
  float* h0  = ws;                                 // N*64
  unsigned* mm0 = (unsigned*)(h0 + N * 64);        // MM_REP*128
  unsigned* mm1 = mm0 + MM_REP * 128;              // MM_REP*128 (contiguous w/ mm0)
  float* ss0 = (float*)(mm1 + MM_REP * 128);       // 256
  float* ss1 = ss0 + 256;                          // 256
  float* part = ss1 + 256;                         // MOM_BLOCKS*MOM_STRIDE
  unsigned short* mh = (unsigned short*)(part + MOM_BLOCKS * MOM_STRIDE);  // N*64 bf16
  int* bhist = (int*)(mh + N * 64);                // NBK
  int* bbase = bhist + NBK;                        // NBK+1
  int* gcur  = bbase + NBK + 1;                    // NBK
  int* start = gcur + NBK;                         // N
  int* segend = start + N;                         // N
  unsigned* packed = (unsigned*)(segend + N);      // E
  unsigned short* srcs = (unsigned short*)(packed + E);  // E

  float* out = (float*)d_out;

  const int row_blocks = (N + 63) / 64;
  const int chunk_blocks = (E + 4095) / 4096;
  const int agg_blocks = (N + 3) / 4;

  // ---- bucket-sorted CSR build (edge structure is layer-invariant) ----
  hipMemsetAsync(bhist, 0, NBK * sizeof(int), stream);
  bucket_hist_kernel<<<chunk_blocks, 256, 0, stream>>>(dst, bhist, E, mm0);
  bucket_scan_kernel<<<1, 64, 0, stream>>>(bhist, bbase, gcur);
  bucket_scatter_kernel<<<chunk_blocks, 256, 0, stream>>>(src, dst, gcur, packed, E);
  bucket_place_kernel<<<NBK, 256, 0, stream>>>(packed, bbase, start, segend, srcs, N);

  // ---- layer 0 ----
  colminmax_kernel<<<256, 256, 0, stream>>>(x0, mm0, mh, N);
  aggregate_kernel<<<agg_blocks, 256, 0, stream>>>(x0, (const uint2*)mh, start,
                                                   segend, srcs, tptr, 0, mm0, h0, N);
  moments_kernel<<<MOM_BLOCKS, 256, 0, stream>>>(h0, part);
  stats_kernel<<<1, 256, 0, stream>>>(part, W1, b1, gamma, beta, 0, ss0);
  fused_mlp_kernel<<<row_blocks, 256, 0, stream>>>(h0, W1, b1, ss0, W2, b2,
                                                   out, N, mm1, mh);
  // ---- layer 1 ----
  aggregate_kernel<<<agg_blocks, 256, 0, stream>>>(out, (const uint2*)mh, start,
                                                   segend, srcs, tptr, 1, mm1, h0, N);
  moments_kernel<<<MOM_BLOCKS, 256, 0, stream>>>(h0, part);
  stats_kernel<<<1, 256, 0, stream>>>(part, W1 + 8192, b1 + 128, gamma, beta, 1, ss1);
  fused_mlp_kernel<<<row_blocks, 256, 0, stream>>>(h0, W1 + 8192, b1 + 128, ss1,
                                                   W2 + 8192, b2 + 64, out, N,
                                                   (unsigned*)0, (unsigned short*)0);
}

// Round 7
// 371.624 us; speedup vs baseline: 1.1669x; 1.1669x over previous
//
#include <hip/hip_runtime.h>
#include <math.h>

#define NN 50000
#define EPSM 1e-7f
#define BN_EPS 1e-5f
#define NBK 391                 // ceil(50000/128) buckets of 128 nodes
#define LOG2E 1.44269504088896340736f
#define MM_REP 8                // mm replicas (colmin/max) to avoid atomic storms
#define MOM_BLOCKS 196          // moments blocks (256 rows each)
#define MG_REP 8                // moment accumulator replicas [8][4160]
#define MG_STRIDE 4160          // 4096 M + 64 colsum

// native 2^x : v_exp_f32 (arg <= 0 here; FTZ for very negative arg is fine).
#if defined(__has_builtin)
#if __has_builtin(__builtin_amdgcn_exp2f)
#define HAVE_EXP2_BUILTIN 1
#endif
#endif
__device__ __forceinline__ float fast_exp2(float v){
#ifdef HAVE_EXP2_BUILTIN
  return __builtin_amdgcn_exp2f(v);
#else
  return exp2f(v);
#endif
}

// ---------------- bucket-sorted CSR build (line-coalesced writes) ----------------

__global__ __launch_bounds__(256) void bucket_hist_kernel(
    const int* __restrict__ dst, int* __restrict__ bhist, int E,
    unsigned* __restrict__ mm0){
  __shared__ int h[NBK];
  int t = threadIdx.x;
  if (blockIdx.x == 0){
    // seed mm0 AND mm1 (contiguous): min seed FLT_MAX / max seed 0
    for (int i = t; i < 2 * MM_REP * 128; i += 256)
      mm0[i] = ((i & 127) < 64) ? 0x7F7FFFFFu : 0u;
  }
  for (int i = t; i < NBK; i += 256) h[i] = 0;
  __syncthreads();
  int e0 = blockIdx.x * 4096;
  int cnt = min(4096, E - e0);
  for (int i = t; i < cnt; i += 256) atomicAdd(&h[dst[e0 + i] >> 7], 1);
  __syncthreads();
  for (int i = t; i < NBK; i += 256) if (h[i]) atomicAdd(&bhist[i], h[i]);
}

__global__ void bucket_scan_kernel(const int* __restrict__ bhist,
                                   int* __restrict__ bbase, int* __restrict__ gcur){
  int lane = threadIdx.x;   // 64 threads
  int loc[7]; int s = 0;
#pragma unroll
  for (int k = 0; k < 7; ++k){
    int i = lane * 7 + k;
    int v = (i < NBK) ? bhist[i] : 0;
    loc[k] = s; s += v;
  }
  int sc = s;
#pragma unroll
  for (int o = 1; o < 64; o <<= 1){
    int n = __shfl_up(sc, o);
    if (lane >= o) sc += n;
  }
  int exc = sc - s;
#pragma unroll
  for (int k = 0; k < 7; ++k){
    int i = lane * 7 + k;
    if (i < NBK){ bbase[i] = exc + loc[k]; gcur[i] = exc + loc[k]; }
    else if (i == NBK) bbase[i] = exc + loc[k];   // total == E
  }
}

__global__ __launch_bounds__(256) void bucket_scatter_kernel(
    const int* __restrict__ src, const int* __restrict__ dst,
    int* __restrict__ gcur, unsigned* __restrict__ packed_g, int E){
  __shared__ int hist[NBK], offs[NBK], gb[NBK], curk[NBK];
  __shared__ unsigned stage[4096];
  __shared__ int gpos[4096];
  int t = threadIdx.x;
  for (int i = t; i < NBK; i += 256) hist[i] = 0;
  __syncthreads();
  int e0 = blockIdx.x * 4096;
  int cnt = min(4096, E - e0);
  unsigned pk[16]; int bk[16];
  int nmine = 0;
  for (int i = t; i < cnt; i += 256){
    int d = dst[e0 + i], s = src[e0 + i];
    pk[nmine] = ((unsigned)d << 16) | (unsigned)s;
    bk[nmine] = d >> 7;
    atomicAdd(&hist[bk[nmine]], 1);
    ++nmine;
  }
  __syncthreads();
  if (t < 64){                      // wave-0 scan of 391 counts (7 per lane)
    int loc[7]; int s = 0;
#pragma unroll
    for (int k = 0; k < 7; ++k){
      int i = t * 7 + k;
      int v = (i < NBK) ? hist[i] : 0;
      loc[k] = s; s += v;
    }
    int sc = s;
#pragma unroll
    for (int o = 1; o < 64; o <<= 1){
      int n = __shfl_up(sc, o);
      if (t >= o) sc += n;
    }
    int exc = sc - s;
#pragma unroll
    for (int k = 0; k < 7; ++k){
      int i = t * 7 + k;
      if (i < NBK) offs[i] = exc + loc[k];
    }
  }
  __syncthreads();
  for (int i = t; i < NBK; i += 256){
    int h = hist[i];
    gb[i] = h ? atomicAdd(&gcur[i], h) : 0;
    curk[i] = offs[i];
  }
  __syncthreads();
  for (int k = 0; k < nmine; ++k){
    int b = bk[k];
    int p = atomicAdd(&curk[b], 1);
    stage[p] = pk[k];
    gpos[p] = gb[b] + (p - offs[b]);
  }
  __syncthreads();
  for (int j = t; j < cnt; j += 256) packed_g[gpos[j]] = stage[j];   // run-coalesced
}

__global__ __launch_bounds__(256) void bucket_place_kernel(
    const unsigned* __restrict__ packed_g, const int* __restrict__ bbase,
    int* __restrict__ start_g, int* __restrict__ end_g,
    unsigned short* __restrict__ srcs_g, int N){
  __shared__ int deg[128], off[128], cur[128];
  __shared__ int sstage[4096];
  int b = blockIdx.x, t = threadIdx.x;
  int beg = bbase[b], cnt = bbase[b + 1] - beg;
  if (t < 128) deg[t] = 0;
  __syncthreads();
  for (int j = t; j < cnt; j += 256)
    atomicAdd(&deg[(packed_g[beg + j] >> 16) & 127], 1);
  __syncthreads();
  if (t < 64){                      // wave-0 scan of 128 (2 per lane)
    int i0 = t * 2;
    int v0 = deg[i0], v1 = deg[i0 + 1];
    int s = v0 + v1;
    int sc = s;
#pragma unroll
    for (int o = 1; o < 64; o <<= 1){
      int n = __shfl_up(sc, o);
      if (t >= o) sc += n;
    }
    int exc = sc - s;
    off[i0] = exc; off[i0 + 1] = exc + v0;
  }
  __syncthreads();
  int node0 = b * 128;
  if (t < 128){
    int node = node0 + t;
    if (node < N){
      start_g[node] = beg + off[t];
      end_g[node] = beg + off[t] + deg[t];
    }
    cur[t] = off[t];
  }
  __syncthreads();
  if (cnt <= 4096){
    for (int j = t; j < cnt; j += 256){
      unsigned p = packed_g[beg + j];
      int lp = atomicAdd(&cur[(p >> 16) & 127], 1);
      sstage[lp] = (int)(p & 0xFFFFu);
    }
    __syncthreads();
    for (int j = t; j < cnt; j += 256)
      srcs_g[beg + j] = (unsigned short)sstage[j];   // coalesced
  } else {                          // freak-bucket fallback (never for random graph)
    for (int j = t; j < cnt; j += 256){
      unsigned p = packed_g[beg + j];
      int lp = atomicAdd(&cur[(p >> 16) & 127], 1);
      srcs_g[beg + lp] = (unsigned short)(p & 0xFFFFu);
    }
  }
}

// ---------------- layer-0 only: bf16 message table [node][64] + column min/max ----

__global__ __launch_bounds__(256) void colminmax_kernel(
    const float* __restrict__ x, unsigned* __restrict__ mm,
    unsigned short* __restrict__ mh, int N){
  __shared__ unsigned smn[256], smx[256];
  int c = threadIdx.x & 63;
  int slot = blockIdx.x * 4 + (threadIdx.x >> 6);
  float mx = 0.f, mn = 1e30f;
  for (int r = slot; r < N; r += 256 * 4){
    float m = fmaxf(x[r * 64 + c], 0.f) + EPSM;
    unsigned u = __float_as_uint(m);
    u += 0x7FFFu + ((u >> 16) & 1u);         // RNE to bf16
    unsigned short us = (unsigned short)(u >> 16);
    mh[r * 64 + c] = us;
    float mb = __uint_as_float(((unsigned)us) << 16);
    mx = fmaxf(mx, mb);
    mn = fminf(mn, mb);
  }
  smn[threadIdx.x] = __float_as_uint(mn);
  smx[threadIdx.x] = __float_as_uint(mx);
  __syncthreads();
  if (threadIdx.x < 64){
    int rep = (blockIdx.x & (MM_REP - 1)) * 128;
    unsigned a = smn[c], b = smn[c + 64], d = smn[c + 128], e = smn[c + 192];
    atomicMin(&mm[rep + c], min(min(a, b), min(d, e)));
    a = smx[c]; b = smx[c + 64]; d = smx[c + 128]; e = smx[c + 192];
    atomicMax(&mm[rep + 64 + c], max(max(a, b), max(d, e)));
  }
}

// ------------- single-pass softmax aggregation -------------
// wave = 4 edge slots x 16 lanes; lane loads a uint2 = 4 bf16 channels. Native
// v_exp_f32 in exp2 domain; per-channel bound B from LDS (block-level reduce).

__global__ __launch_bounds__(256) void aggregate_kernel(
    const float* __restrict__ x, const uint2* __restrict__ mh2,
    const int* __restrict__ start, const int* __restrict__ segend,
    const unsigned short* __restrict__ srcs, const float* __restrict__ tptr,
    int layer, const unsigned* __restrict__ mm, float* __restrict__ h0, int N){
  __shared__ float4 Bs4[16];                // B[64] per-channel log2-domain bound
  int t = threadIdx.x;
  float t2 = tptr[layer] * LOG2E;
  if (t < 64){
    unsigned mn = 0x7F7FFFFFu, mx = 0u;     // positive floats: uint cmp == float cmp
#pragma unroll
    for (int r = 0; r < MM_REP; ++r){
      mn = min(mn, mm[r * 128 + t]);
      mx = max(mx, mm[r * 128 + 64 + t]);
    }
    ((float*)Bs4)[t] = fmaxf(t2 * __uint_as_float(mx), t2 * __uint_as_float(mn));
  }
  __syncthreads();
  int node = blockIdx.x * 4 + (t >> 6);
  if (node >= N) return;
  int lane = t & 63;
  int slot = lane >> 4, cp = lane & 15;     // channels 4cp .. 4cp+3
  float4 B = Bs4[cp];
  int beg = start[node], end = segend[node];
  float d0 = 0.f, d1 = 0.f, d2 = 0.f, d3 = 0.f;
  float n0 = 0.f, n1 = 0.f, n2 = 0.f, n3 = 0.f;
  int e = beg;
  for (; e + 7 < end; e += 8){              // 8 edges per wave-iteration
    int sA = srcs[e + slot];
    int sB = srcs[e + 4 + slot];
    uint2 uA = mh2[sA * 16 + cp];
    uint2 uB = mh2[sB * 16 + cp];
    float a0 = __uint_as_float(uA.x << 16), a1 = __uint_as_float(uA.x & 0xFFFF0000u);
    float a2 = __uint_as_float(uA.y << 16), a3 = __uint_as_float(uA.y & 0xFFFF0000u);
    float b0 = __uint_as_float(uB.x << 16), b1 = __uint_as_float(uB.x & 0xFFFF0000u);
    float b2 = __uint_as_float(uB.y << 16), b3 = __uint_as_float(uB.y & 0xFFFF0000u);
    float pA0 = fast_exp2(fmaf(a0, t2, -B.x)), pA1 = fast_exp2(fmaf(a1, t2, -B.y));
    float pA2 = fast_exp2(fmaf(a2, t2, -B.z)), pA3 = fast_exp2(fmaf(a3, t2, -B.w));
    float pB0 = fast_exp2(fmaf(b0, t2, -B.x)), pB1 = fast_exp2(fmaf(b1, t2, -B.y));
    float pB2 = fast_exp2(fmaf(b2, t2, -B.z)), pB3 = fast_exp2(fmaf(b3, t2, -B.w));
    d0 += pA0 + pB0; n0 += a0 * pA0 + b0 * pB0;
    d1 += pA1 + pB1; n1 += a1 * pA1 + b1 * pB1;
    d2 += pA2 + pB2; n2 += a2 * pA2 + b2 * pB2;
    d3 += pA3 + pB3; n3 += a3 * pA3 + b3 * pB3;
  }
  for (; e + slot < end; e += 4){           // tail: up to 7 edges
    int s = srcs[e + slot];
    uint2 u = mh2[s * 16 + cp];
    float a0 = __uint_as_float(u.x << 16), a1 = __uint_as_float(u.x & 0xFFFF0000u);
    float a2 = __uint_as_float(u.y << 16), a3 = __uint_as_float(u.y & 0xFFFF0000u);
    float p0 = fast_exp2(fmaf(a0, t2, -B.x)), p1 = fast_exp2(fmaf(a1, t2, -B.y));
    float p2 = fast_exp2(fmaf(a2, t2, -B.z)), p3 = fast_exp2(fmaf(a3, t2, -B.w));
    d0 += p0; n0 += a0 * p0;  d1 += p1; n1 += a1 * p1;
    d2 += p2; n2 += a2 * p2;  d3 += p3; n3 += a3 * p3;
  }
  d0 += __shfl_xor(d0, 16); d1 += __shfl_xor(d1, 16);
  d2 += __shfl_xor(d2, 16); d3 += __shfl_xor(d3, 16);
  n0 += __shfl_xor(n0, 16); n1 += __shfl_xor(n1, 16);
  n2 += __shfl_xor(n2, 16); n3 += __shfl_xor(n3, 16);
  d0 += __shfl_xor(d0, 32); d1 += __shfl_xor(d1, 32);
  d2 += __shfl_xor(d2, 32); d3 += __shfl_xor(d3, 32);
  n0 += __shfl_xor(n0, 32); n1 += __shfl_xor(n1, 32);
  n2 += __shfl_xor(n2, 32); n3 += __shfl_xor(n3, 32);
  if (slot == 0){
    float4 xv = ((const float4*)x)[node * 16 + cp];
    float4 o;
    o.x = n0 / (d0 + 1e-16f) + xv.x;
    o.y = n1 / (d1 + 1e-16f) + xv.y;
    o.z = n2 / (d2 + 1e-16f) + xv.z;
    o.w = n3 / (d3 + 1e-16f) + xv.w;
    ((float4*)h0)[node * 16 + cp] = o;
  }
}

// ---------------- moments: M = h0^T h0 and colsum s, replicated-atomic --------
// 196 blocks x 256 rows; each thread owns a 4x4 tile of M in registers, then
// atomicAdds into Mg[blockIdx&7] (XCD-local replica, ~25 writers/address).

__global__ __launch_bounds__(256) void moments_kernel(
    const float* __restrict__ h0, float* __restrict__ Mg){
  __shared__ float rs[16][64];
  int t = threadIdx.x;
  float m[4][4];
#pragma unroll
  for (int a = 0; a < 4; ++a)
#pragma unroll
    for (int b = 0; b < 4; ++b) m[a][b] = 0.f;
  float cs = 0.f;
  int i0 = (t >> 4) * 4, j0 = (t & 15) * 4;
  int lr = t >> 4, lq = t & 15;             // staging: row lr, float4 lq
  int ch = t & 63, r0 = t >> 6;             // colsum: channel ch, rows r0,r0+4,..
  int base = blockIdx.x * 256;
  for (int c = 0; c < 16; ++c){
    __syncthreads();
    int gr = base + c * 16 + lr;
    float4 v = make_float4(0.f, 0.f, 0.f, 0.f);
    if (gr < NN) v = ((const float4*)h0)[gr * 16 + lq];
    *(float4*)&rs[lr][lq * 4] = v;
    __syncthreads();
#pragma unroll
    for (int rr = 0; rr < 16; ++rr){
      float4 av = *(const float4*)&rs[rr][i0];
      float4 bv = *(const float4*)&rs[rr][j0];
      m[0][0] += av.x * bv.x; m[0][1] += av.x * bv.y;
      m[0][2] += av.x * bv.z; m[0][3] += av.x * bv.w;
      m[1][0] += av.y * bv.x; m[1][1] += av.y * bv.y;
      m[1][2] += av.y * bv.z; m[1][3] += av.y * bv.w;
      m[2][0] += av.z * bv.x; m[2][1] += av.z * bv.y;
      m[2][2] += av.z * bv.z; m[2][3] += av.z * bv.w;
      m[3][0] += av.w * bv.x; m[3][1] += av.w * bv.y;
      m[3][2] += av.w * bv.z; m[3][3] += av.w * bv.w;
    }
    cs += rs[r0][ch] + rs[r0 + 4][ch] + rs[r0 + 8][ch] + rs[r0 + 12][ch];
  }
  float* pb = Mg + (blockIdx.x & (MG_REP - 1)) * MG_STRIDE;
#pragma unroll
  for (int a = 0; a < 4; ++a){
    atomicAdd(&pb[(i0 + a) * 64 + j0 + 0], m[a][0]);
    atomicAdd(&pb[(i0 + a) * 64 + j0 + 1], m[a][1]);
    atomicAdd(&pb[(i0 + a) * 64 + j0 + 2], m[a][2]);
    atomicAdd(&pb[(i0 + a) * 64 + j0 + 3], m[a][3]);
  }
  atomicAdd(&pb[4096 + ch], cs);
}

// ---------------- stats: reduce 8 replicas, compute BN scale/shift -----------
// 1 block, 133 KB read. var_j = (w_j^T M w_j + 2 b_j s^T w_j)/N + b_j^2 - mean^2.

__global__ __launch_bounds__(256) void stats_kernel(
    const float* __restrict__ Mg, const float* __restrict__ W1,
    const float* __restrict__ b1, const float* __restrict__ gamma,
    const float* __restrict__ beta, int layer, float* __restrict__ ssg){
  __shared__ float M[64][64];
  __shared__ float s[64];
  __shared__ float w[64][128];
  __shared__ float qp[2][128], swp[2][128];
  int t = threadIdx.x;
  int i0 = (t >> 4) * 4, j0 = (t & 15) * 4;
#pragma unroll
  for (int a = 0; a < 4; ++a){
    float4 acc = make_float4(0.f, 0.f, 0.f, 0.f);
#pragma unroll
    for (int r = 0; r < MG_REP; ++r){
      float4 v = *(const float4*)&Mg[r * MG_STRIDE + (i0 + a) * 64 + j0];
      acc.x += v.x; acc.y += v.y; acc.z += v.z; acc.w += v.w;
    }
    *(float4*)&M[i0 + a][j0] = acc;
  }
  if (t < 64){
    float v = 0.f;
#pragma unroll
    for (int r = 0; r < MG_REP; ++r) v += Mg[r * MG_STRIDE + 4096 + t];
    s[t] = v;
  }
  const float4* wg = (const float4*)W1;
  for (int i = t; i < 2048; i += 256) ((float4*)w)[i] = wg[i];
  __syncthreads();
  int j = t & 127, half = t >> 7;
  float q = 0.f, sw = 0.f;
  for (int i = half * 32; i < half * 32 + 32; ++i){
    float dot = 0.f;
#pragma unroll 8
    for (int k = 0; k < 64; ++k) dot += M[i][k] * w[k][j];
    q += w[i][j] * dot;
  }
  for (int k = half * 32; k < half * 32 + 32; ++k) sw += s[k] * w[k][j];
  qp[half][j] = q; swp[half][j] = sw;
  __syncthreads();
  if (t < 128){
    float qt = qp[0][t] + qp[1][t];
    float swt = swp[0][t] + swp[1][t];
    float bj = b1[t];
    float invN = 1.f / (float)NN;
    float mean = swt * invN + bj;
    float e2 = (qt + 2.f * bj * swt) * invN + bj * bj;
    float var = fmaxf(e2 - mean * mean, 0.f);
    float sc = gamma[layer * 128 + t] / sqrtf(var + BN_EPS);
    ssg[t] = sc;
    ssg[128 + t] = beta[layer * 128 + t] - mean * sc;
  }
}

// ---------------- fused MLP: out = relu( relu(BN(h0@W1+b1)) @ W2 + b2 ) -------
// BN scale/shift precomputed (ssg). h1 never touches HBM: gemm1 accumulators
// are BN+relu'd in registers, staged to LDS, consumed by gemm2 in-place.
// Layer 0 also emits next layer's bf16 message table + column min/max.

__global__ __launch_bounds__(256) void fused_mlp_kernel(
    const float* __restrict__ h0, const float* __restrict__ W1,
    const float* __restrict__ b1, const float* __restrict__ ssg,
    const float* __restrict__ W2, const float* __restrict__ b2,
    float* __restrict__ xout, int N,
    unsigned* __restrict__ mm_next, unsigned short* __restrict__ mh_next){
  __shared__ float lds[64 * 132];   // phase A: [64][68] h0 tile; phase B: [64][132] h1'
  __shared__ float ss[256];
  __shared__ unsigned smn[64], smx[64];
  int t = threadIdx.x;
  ss[t] = ssg[t];
  if (t < 64){ smn[t] = 0x7F7FFFFFu; smx[t] = 0u; }
  int row0 = blockIdx.x * 64;
#pragma unroll
  for (int i = 0; i < 4; ++i){
    int li = t + 256 * i;
    int r = li >> 4, q = li & 15;
    int gr = row0 + r;
    float4 v = make_float4(0.f, 0.f, 0.f, 0.f);
    if (gr < N) v = ((const float4*)h0)[gr * 16 + q];
    *(float4*)&lds[r * 68 + q * 4] = v;
  }
  __syncthreads();
  // ---- gemm1: acc1[8][4], rows tr*8.., cols tc*4.. ----
  int tc = t & 31, tr = t >> 5;
  float4 bias1 = ((const float4*)b1)[tc];
  float acc1[8][4];
#pragma unroll
  for (int r = 0; r < 8; ++r){
    acc1[r][0] = bias1.x; acc1[r][1] = bias1.y;
    acc1[r][2] = bias1.z; acc1[r][3] = bias1.w;
  }
  const float4* wg1 = (const float4*)W1;    // [64][32] float4, L1/L2-resident
#pragma unroll 2
  for (int k = 0; k < 64; k += 4){
    float4 w0 = wg1[(k + 0) * 32 + tc];
    float4 w1 = wg1[(k + 1) * 32 + tc];
    float4 w2 = wg1[(k + 2) * 32 + tc];
    float4 w3 = wg1[(k + 3) * 32 + tc];
#pragma unroll
    for (int r = 0; r < 8; ++r){
      float4 a = *(const float4*)&lds[(tr * 8 + r) * 68 + k];
      acc1[r][0] += a.x * w0.x + a.y * w1.x + a.z * w2.x + a.w * w3.x;
      acc1[r][1] += a.x * w0.y + a.y * w1.y + a.z * w2.y + a.w * w3.y;
      acc1[r][2] += a.x * w0.z + a.y * w1.z + a.z * w2.z + a.w * w3.z;
      acc1[r][3] += a.x * w0.w + a.y * w1.w + a.z * w2.w + a.w * w3.w;
    }
  }
  __syncthreads();   // all phase-A reads complete before overwriting LDS
  // ---- BN + relu in registers -> phase-B LDS [64][132] ----
  float4 sc4 = *(const float4*)&ss[tc * 4];
  float4 sh4 = *(const float4*)&ss[128 + tc * 4];
#pragma unroll
  for (int r = 0; r < 8; ++r){
    float4 o;
    o.x = fmaxf(acc1[r][0] * sc4.x + sh4.x, 0.f);
    o.y = fmaxf(acc1[r][1] * sc4.y + sh4.y, 0.f);
    o.z = fmaxf(acc1[r][2] * sc4.z + sh4.z, 0.f);
    o.w = fmaxf(acc1[r][3] * sc4.w + sh4.w, 0.f);
    *(float4*)&lds[(tr * 8 + r) * 132 + tc * 4] = o;
  }
  __syncthreads();
  // ---- gemm2: acc2[4][4], rows tr2*4.., cols tc2*4.. of 64 ----
  int tc2 = t & 15, tr2 = t >> 4;
  float4 bias2 = ((const float4*)b2)[tc2];
  float acc2[4][4];
#pragma unroll
  for (int r = 0; r < 4; ++r){
    acc2[r][0] = bias2.x; acc2[r][1] = bias2.y;
    acc2[r][2] = bias2.z; acc2[r][3] = bias2.w;
  }
  const float4* wg2 = (const float4*)W2;    // [128][16] float4
#pragma unroll 2
  for (int k = 0; k < 128; k += 4){
    float4 w0 = wg2[(k + 0) * 16 + tc2];
    float4 w1 = wg2[(k + 1) * 16 + tc2];
    float4 w2 = wg2[(k + 2) * 16 + tc2];
    float4 w3 = wg2[(k + 3) * 16 + tc2];
#pragma unroll
    for (int r = 0; r < 4; ++r){
      float4 a = *(const float4*)&lds[(tr2 * 4 + r) * 132 + k];
      acc2[r][0] += a.x * w0.x + a.y * w1.x + a.z * w2.x + a.w * w3.x;
      acc2[r][1] += a.x * w0.y + a.y * w1.y + a.z * w2.y + a.w * w3.y;
      acc2[r][2] += a.x * w0.z + a.y * w1.z + a.z * w2.z + a.w * w3.z;
      acc2[r][3] += a.x * w0.w + a.y * w1.w + a.z * w2.w + a.w * w3.w;
    }
  }
  unsigned mnv[4] = {0x7F7FFFFFu, 0x7F7FFFFFu, 0x7F7FFFFFu, 0x7F7FFFFFu};
  unsigned mxv[4] = {0u, 0u, 0u, 0u};
#pragma unroll
  for (int r = 0; r < 4; ++r){
    int gr = row0 + tr2 * 4 + r;
    if (gr < N){
      float o0 = fmaxf(acc2[r][0], 0.f), o1 = fmaxf(acc2[r][1], 0.f);
      float o2 = fmaxf(acc2[r][2], 0.f), o3 = fmaxf(acc2[r][3], 0.f);
      *(float4*)&xout[gr * 64 + tc2 * 4] = make_float4(o0, o1, o2, o3);
      if (mh_next != 0){
        unsigned us[4];
        float ov[4] = {o0, o1, o2, o3};
#pragma unroll
        for (int j = 0; j < 4; ++j){
          unsigned u = __float_as_uint(ov[j] + EPSM);
          u += 0x7FFFu + ((u >> 16) & 1u);       // RNE to bf16
          us[j] = u >> 16;
          unsigned fb = us[j] << 16;
          mnv[j] = min(mnv[j], fb);
          mxv[j] = max(mxv[j], fb);
        }
        ((uint2*)mh_next)[gr * 16 + tc2] =
            make_uint2(us[0] | (us[1] << 16), us[2] | (us[3] << 16));
      }
    }
  }
  if (mh_next != 0){
    __syncthreads();
#pragma unroll
    for (int j = 0; j < 4; ++j){
      atomicMin(&smn[tc2 * 4 + j], mnv[j]);
      atomicMax(&smx[tc2 * 4 + j], mxv[j]);
    }
    __syncthreads();
    if (t < 64){
      int rep = (blockIdx.x & (MM_REP - 1)) * 128;
      atomicMin(&mm_next[rep + t], smn[t]);
      atomicMax(&mm_next[rep + 64 + t], smx[t]);
    }
  }
}

extern "C" void kernel_launch(void* const* d_in, const int* in_sizes, int n_in,
                              void* d_out, int out_size, void* d_ws, size_t ws_size,
                              hipStream_t stream) {
  const float* x0    = (const float*)d_in[0];
  const int*   ei    = (const int*)d_in[1];
  const float* W1    = (const float*)d_in[2];
  const float* b1    = (const float*)d_in[3];
  const float* gamma = (const float*)d_in[4];
  const float* beta  = (const float*)d_in[5];
  const float* W2    = (const float*)d_in[6];
  const float* b2    = (const float*)d_in[7];
  const float* tptr  = (const float*)d_in[8];

  const int N = NN;
  const int E = in_sizes[1] / 2;
  const int* src = ei;
  const int* dst = ei + E;

  float* ws  = (float*)d_ws;
  float* h0  = ws;                                 // N*64
  unsigned* mm0 = (unsigned*)(h0 + N * 64);        // MM_REP*128
  unsigned* mm1 = mm0 + MM_REP * 128;              // MM_REP*128 (contiguous w/ mm0)
  float* ss0 = (float*)(mm1 + MM_REP * 128);       // 256
  float* ss1 = ss0 + 256;                          // 256
  float* Mg0 = ss1 + 256;                          // MG_REP*MG_STRIDE
  float* Mg1 = Mg0 + MG_REP * MG_STRIDE;           // MG_REP*MG_STRIDE
  unsigned short* mh = (unsigned short*)(Mg1 + MG_REP * MG_STRIDE);  // N*64 bf16
  int* bhist = (int*)(mh + N * 64);                // NBK
  int* bbase = bhist + NBK;                        // NBK+1
  int* gcur  = bbase + NBK + 1;                    // NBK
  int* start = gcur + NBK;                         // N
  int* segend = start + N;                         // N
  unsigned* packed = (unsigned*)(segend + N);      // E
  unsigned short* srcs = (unsigned short*)(packed + E);  // E

  float* out = (float*)d_out;

  const int row_blocks = (N + 63) / 64;
  const int chunk_blocks = (E + 4095) / 4096;
  const int agg_blocks = (N + 3) / 4;

  // ---- bucket-sorted CSR build (edge structure is layer-invariant) ----
  hipMemsetAsync(bhist, 0, NBK * sizeof(int), stream);
  hipMemsetAsync(Mg0, 0, 2 * MG_REP * MG_STRIDE * sizeof(float), stream);
  bucket_hist_kernel<<<chunk_blocks, 256, 0, stream>>>(dst, bhist, E, mm0);
  bucket_scan_kernel<<<1, 64, 0, stream>>>(bhist, bbase, gcur);
  bucket_scatter_kernel<<<chunk_blocks, 256, 0, stream>>>(src, dst, gcur, packed, E);
  bucket_place_kernel<<<NBK, 256, 0, stream>>>(packed, bbase, start, segend, srcs, N);

  // ---- layer 0 ----
  colminmax_kernel<<<256, 256, 0, stream>>>(x0, mm0, mh, N);
  aggregate_kernel<<<agg_blocks, 256, 0, stream>>>(x0, (const uint2*)mh, start,
                                                   segend, srcs, tptr, 0, mm0, h0, N);
  moments_kernel<<<MOM_BLOCKS, 256, 0, stream>>>(h0, Mg0);
  stats_kernel<<<1, 256, 0, stream>>>(Mg0, W1, b1, gamma, beta, 0, ss0);
  fused_mlp_kernel<<<row_blocks, 256, 0, stream>>>(h0, W1, b1, ss0, W2, b2,
                                                   out, N, mm1, mh);
  // ---- layer 1 ----
  aggregate_kernel<<<agg_blocks, 256, 0, stream>>>(out, (const uint2*)mh, start,
                                                   segend, srcs, tptr, 1, mm1, h0, N);
  moments_kernel<<<MOM_BLOCKS, 256, 0, stream>>>(h0, Mg1);
  stats_kernel<<<1, 256, 0, stream>>>(Mg1, W1 + 8192, b1 + 128, gamma, beta, 1, ss1);
  fused_mlp_kernel<<<row_blocks, 256, 0, stream>>>(h0, W1 + 8192, b1 + 128, ss1,
                                                   W2 + 8192, b2 + 64, out, N,
                                                   (unsigned*)0, (unsigned short*)0);
}